// Round 1
// baseline (237.540 us; speedup 1.0000x reference)
//
#include <hip/hip_runtime.h>

#define NS 64          // samples = 32 batches * 2 channels
#define HH 640
#define WW 640
#define NPIX (HH * WW)   // 409600
#define TH 320
#define TW 320
#define MINK 10

// bilinear resize (half-pixel centers, edge clamp == torch align_corners=False
// == jax.image.resize bilinear with its edge re-normalization) for 2x upsample
__device__ __forceinline__ float resize_tv(const float* __restrict__ tgt, int y, int xc) {
    float sy = fmaxf(0.5f * (float)y - 0.25f, 0.0f);
    int y0 = (int)sy;
    float fy = sy - (float)y0;
    int y1 = min(y0 + 1, TH - 1);
    float sx = fmaxf(0.5f * (float)xc - 0.25f, 0.0f);
    int x0 = (int)sx;
    float fx = sx - (float)x0;
    int x1 = min(x0 + 1, TW - 1);
    const float* r0 = tgt + y0 * TW;
    const float* r1 = tgt + y1 * TW;
    float top = (1.0f - fx) * r0[x0] + fx * r0[x1];
    float bot = (1.0f - fx) * r1[x0] + fx * r1[x1];
    return (1.0f - fy) * top + fy * bot;
}

// ---------------- pass 1: per-sample streaming reduction ----------------
// ws layout: float wsf[0..63]=sumAll, [64..127]=sumPos, [128..191]=sumNeg,
//            [192..255]=topkSum ; int cnt[0..63]=numPos  (after wsf)
__global__ __launch_bounds__(256) void k_reduce(const float* __restrict__ x,
                                                const float* __restrict__ ct,
                                                const float* __restrict__ at,
                                                float* __restrict__ wsf,
                                                int* __restrict__ cnt) {
    const int blocksPerSample = NPIX / (256 * 4);  // 400
    int s = blockIdx.x / blocksPerSample;
    int chunk = blockIdx.x % blocksPerSample;
    int b = s >> 1, c = s & 1;
    const float* pred = x + (size_t)s * NPIX;
    const float* tgt = (c == 0 ? ct : at) + (size_t)b * (TH * TW);

    int e = (chunk * 256 + threadIdx.x) * 4;   // 4 consecutive x, same row (640%4==0)
    int y = e / WW;
    int xo = e % WW;

    float4 p4 = *reinterpret_cast<const float4*>(pred + e);
    float pv[4] = {p4.x, p4.y, p4.z, p4.w};

    float sAll = 0.0f, sPos = 0.0f, sNeg = 0.0f;
    int cPos = 0;
#pragma unroll
    for (int j = 0; j < 4; ++j) {
        float tv = resize_tv(tgt, y, xo + j);
        float d = pv[j] - tv;
        float l = d * d;
        sAll += l;
        if (tv > 0.0f) { sPos += l; cPos++; } else { sNeg += l; }
    }

    // wave64 shuffle reduce
    for (int off = 32; off > 0; off >>= 1) {
        sAll += __shfl_down(sAll, off);
        sPos += __shfl_down(sPos, off);
        sNeg += __shfl_down(sNeg, off);
        cPos += __shfl_down(cPos, off);
    }
    __shared__ float shA[4], shP[4], shN[4];
    __shared__ int shC[4];
    int wave = threadIdx.x >> 6;
    if ((threadIdx.x & 63) == 0) { shA[wave] = sAll; shP[wave] = sPos; shN[wave] = sNeg; shC[wave] = cPos; }
    __syncthreads();
    if (threadIdx.x == 0) {
        float a = shA[0] + shA[1] + shA[2] + shA[3];
        float p = shP[0] + shP[1] + shP[2] + shP[3];
        float n = shN[0] + shN[1] + shN[2] + shN[3];
        int ci = shC[0] + shC[1] + shC[2] + shC[3];
        atomicAdd(&wsf[s], a);
        atomicAdd(&wsf[64 + s], p);
        atomicAdd(&wsf[128 + s], n);
        atomicAdd(&cnt[s], ci);
    }
}

// ---------------- pass 2 (rare fallback): exact top-k when k < N-p ----------------
// 3-pass bit-histogram selection (11/11/10 bits) over nonneg f32 losses of
// negative-target elements. Early-exits (never runs for this data regime).
__global__ __launch_bounds__(256) void k_topk(const float* __restrict__ x,
                                              const float* __restrict__ ct,
                                              const float* __restrict__ at,
                                              const float* __restrict__ wsf,
                                              const int* __restrict__ cnt,
                                              float* __restrict__ topk) {
    int s = blockIdx.x;
    int p = cnt[s];
    int k = min((int)((float)p * 3.0f), NPIX - p);
    if (k < MINK || k >= NPIX - p) return;   // simple paths handled in k_final

    int b = s >> 1, c = s & 1;
    const float* pred = x + (size_t)s * NPIX;
    const float* tgt = (c == 0 ? ct : at) + (size_t)b * (TH * TW);

    __shared__ unsigned int hcnt[2048];
    __shared__ float hsum[2048];
    __shared__ unsigned int selBin;
    __shared__ unsigned int remShared;
    __shared__ float sumTopShared;

    if (threadIdx.x == 0) { remShared = (unsigned int)k; sumTopShared = 0.0f; }

    const int shiftv[3] = {21, 10, 0};
    const unsigned int maskv[3] = {0x7FFu, 0x7FFu, 0x3FFu};
    unsigned int prefix = 0;

    for (int pass = 0; pass < 3; ++pass) {
        for (int i = threadIdx.x; i < 2048; i += 256) { hcnt[i] = 0u; hsum[i] = 0.0f; }
        __syncthreads();
        for (int e = threadIdx.x; e < NPIX; e += 256) {
            int yy = e / WW, xx = e % WW;
            float tv = resize_tv(tgt, yy, xx);
            if (tv > 0.0f) continue;          // positives excluded (-inf in ref)
            float d = pred[e] - tv;
            float l = d * d;                  // >= 0, so uint bits are order-preserving
            unsigned int bits = __float_as_uint(l);
            bool match;
            if (pass == 0) match = true;
            else if (pass == 1) match = ((bits >> 21) == prefix);
            else match = ((bits >> 10) == prefix);
            if (match) {
                unsigned int bin = (bits >> shiftv[pass]) & maskv[pass];
                atomicAdd(&hcnt[bin], 1u);
                atomicAdd(&hsum[bin], l);
            }
        }
        __syncthreads();
        if (threadIdx.x == 0) {
            unsigned int remS = remShared;
            int nb = (int)maskv[pass] + 1;
            unsigned int cum = 0; float sAbove = 0.0f; unsigned int bsel = 0;
            for (int bin = nb - 1; bin >= 0; --bin) {
                unsigned int cc = hcnt[bin];
                if (cum + cc >= remS) { bsel = (unsigned int)bin; break; }
                cum += cc; sAbove += hsum[bin];
            }
            selBin = bsel;
            remShared = remS - cum;
            sumTopShared += sAbove;
        }
        __syncthreads();
        if (pass == 0) prefix = selBin;
        else if (pass == 1) prefix = (prefix << 11) | selBin;
        __syncthreads();
    }
    if (threadIdx.x == 0) {
        unsigned int bits = (prefix << 10) | selBin;  // exact k-th largest value
        float v = __uint_as_float(bits);
        topk[s] = sumTopShared + (float)remShared * v;
    }
}

// ---------------- pass 3: per-sample OHEM logic + final mean ----------------
__global__ void k_final(const float* __restrict__ wsf, const int* __restrict__ cnt,
                        const float* __restrict__ topk, float* __restrict__ out) {
    int s = threadIdx.x;   // 64 threads == 1 wave
    float lossv;
    {
        int p = cnt[s];
        int k = min((int)((float)p * 3.0f), NPIX - p);  // f32 mult exact (3p < 2^24)
        float sumAll = wsf[s], sumPos = wsf[64 + s], sumNeg = wsf[128 + s];
        if (k < MINK) {
            lossv = sumAll / (float)NPIX;
        } else {
            float tsum = (k >= NPIX - p) ? sumNeg : topk[s];
            lossv = sumPos / (float)max(p, 1) + tsum / (float)max(k, 1);
        }
    }
    for (int off = 32; off > 0; off >>= 1) lossv += __shfl_down(lossv, off);
    if (s == 0) out[0] = lossv / 32.0f;   // mean over B of (char + aff)
}

extern "C" void kernel_launch(void* const* d_in, const int* in_sizes, int n_in,
                              void* d_out, int out_size, void* d_ws, size_t ws_size,
                              hipStream_t stream) {
    const float* x  = (const float*)d_in[0];
    const float* ct = (const float*)d_in[1];
    const float* at = (const float*)d_in[2];
    float* out = (float*)d_out;

    float* wsf = (float*)d_ws;            // 256 floats
    int* cnt = (int*)((char*)d_ws + 256 * sizeof(float));  // 64 ints

    hipMemsetAsync(d_ws, 0, 256 * sizeof(float) + 64 * sizeof(int), stream);

    const int blocksPerSample = NPIX / (256 * 4);  // 400
    k_reduce<<<dim3(NS * blocksPerSample), dim3(256), 0, stream>>>(x, ct, at, wsf, cnt);
    k_topk<<<dim3(NS), dim3(256), 0, stream>>>(x, ct, at, wsf, cnt, wsf + 192);
    k_final<<<dim3(1), dim3(64), 0, stream>>>(wsf, cnt, wsf + 192, out);
}

// Round 2
// 50.171 us; speedup vs baseline: 4.7346x; 4.7346x over previous
//
#include <hip/hip_runtime.h>

#define NS 64          // samples = 32 batches * 2 channels
#define HH 640
#define WW 640
#define NPIX (HH * WW)   // 409600
#define TH 320
#define TW 320
#define MINK 10
#define BPS 40               // blocks per sample
#define PXB (NPIX / BPS)     // 10240 px per block (16 rows)
#define GRP (PXB / (256 * 4))// 10 float4-groups per thread

typedef float ufloat4 __attribute__((ext_vector_type(4), aligned(4)));

// exact scalar bilinear tap (half-pixel centers, edge clamp) — edge fallback
__device__ __forceinline__ float resize_scalar(const float* __restrict__ tgt, int y, int xc) {
    float sy = fmaxf(0.5f * (float)y - 0.25f, 0.0f);
    int y0 = (int)sy;
    float fy = sy - (float)y0;
    int y1 = min(y0 + 1, TH - 1);
    float sx = fmaxf(0.5f * (float)xc - 0.25f, 0.0f);
    int x0 = (int)sx;
    float fx = sx - (float)x0;
    int x1 = min(x0 + 1, TW - 1);
    const float* r0 = tgt + y0 * TW;
    const float* r1 = tgt + y1 * TW;
    float top = (1.0f - fx) * r0[x0] + fx * r0[x1];
    float bot = (1.0f - fx) * r1[x0] + fx * r1[x1];
    return (1.0f - fy) * top + fy * bot;
}

// ---------------- pass 1: per-sample streaming reduction ----------------
// partials per block: partA/partP/partN[s*BPS+blk]; cnt[s] via int atomics.
__global__ __launch_bounds__(256) void k_reduce(const float* __restrict__ x,
                                                const float* __restrict__ ct,
                                                const float* __restrict__ at,
                                                float* __restrict__ partA,
                                                float* __restrict__ partP,
                                                float* __restrict__ partN,
                                                int* __restrict__ cnt) {
    int bid = blockIdx.x;
    int s = bid / BPS, blk = bid % BPS;
    int b = s >> 1, c = s & 1;
    const float* pred = x + (size_t)s * NPIX;
    const float* tgt = (c == 0 ? ct : at) + (size_t)b * (TH * TW);

    float sA = 0.0f, sP = 0.0f, sN = 0.0f;
    int cP = 0;

#pragma unroll 2
    for (int i = 0; i < GRP; ++i) {
        int e = blk * PXB + (i * 256 + (int)threadIdx.x) * 4;
        int y = e / WW, xo = e % WW;
        float4 p4 = *reinterpret_cast<const float4*>(pred + e);

        float sy = fmaxf(0.5f * (float)y - 0.25f, 0.0f);
        int y0 = (int)sy;
        float fy = sy - (float)y0;
        int y1 = min(y0 + 1, TH - 1);
        const float* r0 = tgt + y0 * TW;
        const float* r1 = tgt + y1 * TW;

        float tv0, tv1, tv2, tv3;
        int m = xo >> 1;
        if (xo > 0 && xo < WW - 4) {
            // interior: x-weights are exactly {0.75,0.25,0.75,0.25}; need cols m-1..m+2
            ufloat4 g0 = *reinterpret_cast<const ufloat4*>(r0 + m - 1);
            ufloat4 g1 = *reinterpret_cast<const ufloat4*>(r1 + m - 1);
            float t0 = 0.25f * g0.x + 0.75f * g0.y;
            float t1 = 0.75f * g0.y + 0.25f * g0.z;
            float t2 = 0.25f * g0.y + 0.75f * g0.z;
            float t3 = 0.75f * g0.z + 0.25f * g0.w;
            float b0 = 0.25f * g1.x + 0.75f * g1.y;
            float b1 = 0.75f * g1.y + 0.25f * g1.z;
            float b2 = 0.25f * g1.y + 0.75f * g1.z;
            float b3 = 0.75f * g1.z + 0.25f * g1.w;
            float gy = 1.0f - fy;
            tv0 = gy * t0 + fy * b0;
            tv1 = gy * t1 + fy * b1;
            tv2 = gy * t2 + fy * b2;
            tv3 = gy * t3 + fy * b3;
        } else {
            tv0 = resize_scalar(tgt, y, xo + 0);
            tv1 = resize_scalar(tgt, y, xo + 1);
            tv2 = resize_scalar(tgt, y, xo + 2);
            tv3 = resize_scalar(tgt, y, xo + 3);
        }

        float pv[4] = {p4.x, p4.y, p4.z, p4.w};
        float tv[4] = {tv0, tv1, tv2, tv3};
#pragma unroll
        for (int j = 0; j < 4; ++j) {
            float d = pv[j] - tv[j];
            float l = d * d;
            sA += l;
            if (tv[j] > 0.0f) { sP += l; cP++; } else { sN += l; }
        }
    }

    // wave64 shuffle reduce + LDS block reduce
    for (int off = 32; off > 0; off >>= 1) {
        sA += __shfl_down(sA, off);
        sP += __shfl_down(sP, off);
        sN += __shfl_down(sN, off);
        cP += __shfl_down(cP, off);
    }
    __shared__ float shA[4], shP[4], shN[4];
    __shared__ int shC[4];
    int wave = threadIdx.x >> 6;
    if ((threadIdx.x & 63) == 0) { shA[wave] = sA; shP[wave] = sP; shN[wave] = sN; shC[wave] = cP; }
    __syncthreads();
    if (threadIdx.x == 0) {
        partA[s * BPS + blk] = shA[0] + shA[1] + shA[2] + shA[3];
        partP[s * BPS + blk] = shP[0] + shP[1] + shP[2] + shP[3];
        partN[s * BPS + blk] = shN[0] + shN[1] + shN[2] + shN[3];
        atomicAdd(&cnt[s], shC[0] + shC[1] + shC[2] + shC[3]);
    }
}

// ---------------- pass 2 (rare fallback): exact top-k when k < N-p ----------------
// 3-pass bit-histogram selection over losses of negative-target elements.
// Early-exits for this data regime (p ~ N/2 >> N/4).
__global__ __launch_bounds__(256) void k_topk(const float* __restrict__ x,
                                              const float* __restrict__ ct,
                                              const float* __restrict__ at,
                                              const int* __restrict__ cnt,
                                              float* __restrict__ topk) {
    int s = blockIdx.x;
    int p = cnt[s];
    int k = min((int)((float)p * 3.0f), NPIX - p);
    if (k < MINK || k >= NPIX - p) return;   // simple paths handled in k_final

    int b = s >> 1, c = s & 1;
    const float* pred = x + (size_t)s * NPIX;
    const float* tgt = (c == 0 ? ct : at) + (size_t)b * (TH * TW);

    __shared__ unsigned int hcnt[2048];
    __shared__ float hsum[2048];
    __shared__ unsigned int selBin;
    __shared__ unsigned int remShared;
    __shared__ float sumTopShared;

    if (threadIdx.x == 0) { remShared = (unsigned int)k; sumTopShared = 0.0f; }

    const int shiftv[3] = {21, 10, 0};
    const unsigned int maskv[3] = {0x7FFu, 0x7FFu, 0x3FFu};
    unsigned int prefix = 0;

    for (int pass = 0; pass < 3; ++pass) {
        for (int i = threadIdx.x; i < 2048; i += 256) { hcnt[i] = 0u; hsum[i] = 0.0f; }
        __syncthreads();
        for (int e = threadIdx.x; e < NPIX; e += 256) {
            int yy = e / WW, xx = e % WW;
            float tv = resize_scalar(tgt, yy, xx);
            if (tv > 0.0f) continue;          // positives excluded (-inf in ref)
            float d = pred[e] - tv;
            float l = d * d;                  // >= 0: uint bits order-preserving
            unsigned int bits = __float_as_uint(l);
            bool match;
            if (pass == 0) match = true;
            else if (pass == 1) match = ((bits >> 21) == prefix);
            else match = ((bits >> 10) == prefix);
            if (match) {
                unsigned int bin = (bits >> shiftv[pass]) & maskv[pass];
                atomicAdd(&hcnt[bin], 1u);
                atomicAdd(&hsum[bin], l);
            }
        }
        __syncthreads();
        if (threadIdx.x == 0) {
            unsigned int remS = remShared;
            int nb = (int)maskv[pass] + 1;
            unsigned int cum = 0; float sAbove = 0.0f; unsigned int bsel = 0;
            for (int bin = nb - 1; bin >= 0; --bin) {
                unsigned int cc = hcnt[bin];
                if (cum + cc >= remS) { bsel = (unsigned int)bin; break; }
                cum += cc; sAbove += hsum[bin];
            }
            selBin = bsel;
            remShared = remS - cum;
            sumTopShared += sAbove;
        }
        __syncthreads();
        if (pass == 0) prefix = selBin;
        else if (pass == 1) prefix = (prefix << 11) | selBin;
        __syncthreads();
    }
    if (threadIdx.x == 0) {
        unsigned int bits = (prefix << 10) | selBin;  // exact k-th largest value
        float v = __uint_as_float(bits);
        topk[s] = sumTopShared + (float)remShared * v;
    }
}

// ---------------- pass 3: sum partials, per-sample OHEM logic, final mean ----------------
__global__ void k_final(const float* __restrict__ partA, const float* __restrict__ partP,
                        const float* __restrict__ partN, const int* __restrict__ cnt,
                        const float* __restrict__ topk, float* __restrict__ out) {
    int s = threadIdx.x;   // 64 threads == 1 wave
    float a = 0.0f, pp = 0.0f, nn = 0.0f;
    for (int bq = 0; bq < BPS; ++bq) {
        a += partA[s * BPS + bq];
        pp += partP[s * BPS + bq];
        nn += partN[s * BPS + bq];
    }
    int p = cnt[s];
    int k = min((int)((float)p * 3.0f), NPIX - p);  // exact: 3p < 2^24
    float lossv;
    if (k < MINK) {
        lossv = a / (float)NPIX;
    } else {
        float tsum = (k >= NPIX - p) ? nn : topk[s];
        lossv = pp / (float)max(p, 1) + tsum / (float)max(k, 1);
    }
    for (int off = 32; off > 0; off >>= 1) lossv += __shfl_down(lossv, off);
    if (s == 0) out[0] = lossv / 32.0f;   // mean over B of (char + aff)
}

extern "C" void kernel_launch(void* const* d_in, const int* in_sizes, int n_in,
                              void* d_out, int out_size, void* d_ws, size_t ws_size,
                              hipStream_t stream) {
    const float* x  = (const float*)d_in[0];
    const float* ct = (const float*)d_in[1];
    const float* at = (const float*)d_in[2];
    float* out = (float*)d_out;

    float* partA = (float*)d_ws;                 // NS*BPS floats
    float* partP = partA + NS * BPS;             // NS*BPS floats
    float* partN = partP + NS * BPS;             // NS*BPS floats
    float* topk  = partN + NS * BPS;             // NS floats
    int*   cnt   = (int*)(topk + NS);            // NS ints

    hipMemsetAsync(cnt, 0, NS * sizeof(int), stream);

    k_reduce<<<dim3(NS * BPS), dim3(256), 0, stream>>>(x, ct, at, partA, partP, partN, cnt);
    k_topk<<<dim3(NS), dim3(256), 0, stream>>>(x, ct, at, cnt, topk);
    k_final<<<dim3(1), dim3(64), 0, stream>>>(partA, partP, partN, cnt, topk, out);
}

// Round 3
// 30.839 us; speedup vs baseline: 7.7025x; 1.6269x over previous
//
#include <hip/hip_runtime.h>

#define NS 64            // samples = 32 batches * 2 channels
#define HH 640
#define WW 640
#define NPIX (HH * WW)   // 409600
#define TH 320
#define TW 320
#define MINK 10
#define BPS 40           // blocks per sample (16 rows each)
#define TPB 320          // 4 rows x 80 u-slots, 5 waves
#define ITERS 4          // 4 row-steps of 4 rows = 16 rows

// exact scalar bilinear tap (half-pixel centers, edge clamp) — fallback path only
__device__ __forceinline__ float resize_scalar(const float* __restrict__ tgt, int y, int xc) {
    float sy = fmaxf(0.5f * (float)y - 0.25f, 0.0f);
    int y0 = (int)sy;
    float fy = sy - (float)y0;
    int y1 = min(y0 + 1, TH - 1);
    float sx = fmaxf(0.5f * (float)xc - 0.25f, 0.0f);
    int x0 = (int)sx;
    float fx = sx - (float)x0;
    int x1 = min(x0 + 1, TW - 1);
    const float* r0 = tgt + y0 * TW;
    const float* r1 = tgt + y1 * TW;
    float top = (1.0f - fx) * r0[x0] + fx * r0[x1];
    float bot = (1.0f - fx) * r1[x0] + fx * r1[x1];
    return (1.0f - fy) * top + fy * bot;
}

// ---------------- pass 1: per-sample streaming reduction ----------------
// All loads aligned; all per-iter addressing is incremental. Per-block
// partials (no atomics, no ws init needed).
__global__ __launch_bounds__(TPB) void k_reduce(const float* __restrict__ x,
                                                const float* __restrict__ ct,
                                                const float* __restrict__ at,
                                                float* __restrict__ partA,
                                                float* __restrict__ partP,
                                                int* __restrict__ partC) {
    int bid = blockIdx.x;
    int s = bid / BPS, blk = bid % BPS;
    int b = s >> 1, c = s & 1;
    const float* pred = x + (size_t)s * NPIX;
    const float* tgt = (c == 0 ? ct : at) + (size_t)b * (TH * TW);

    int tid = threadIdx.x;
    int u = tid % 80;        // output col group: x = 8u..8u+7
    int rr = tid / 80;       // 0..3
    int rbase = blk * 16;

    // y parity = rr parity (rbase even): fy fixed per thread
    float fy = (rr & 1) ? 0.25f : 0.75f;
    float gy = 1.0f - fy;
    // tgt cols: aligned quad [4u..4u+3] + clamped edge dwords (clamping == resize edge semantics)
    int xq = 4 * u;
    int xl = max(xq - 1, 0);
    int xr = min(xq + 4, TW - 1);

    float sA = 0.0f, sP = 0.0f;
    int cP = 0;

#pragma unroll
    for (int i = 0; i < ITERS; ++i) {
        int y = rbase + rr + 4 * i;
        int y0raw = (y >> 1) + (y & 1) - 1;     // y even: y/2-1 (fy=.75); y odd: (y-1)/2 (fy=.25)
        int y0 = max(y0raw, 0);                  // y=0: y0=y1=0 -> pure row0 (matches sy-clamp)
        int y1 = min(y0raw + 1, TH - 1);         // y=639: y1 clamps to 319
        const float* r0 = tgt + y0 * TW;
        const float* r1 = tgt + y1 * TW;

        float4 a4 = *reinterpret_cast<const float4*>(r0 + xq);
        float La = r0[xl], Ra = r0[xr];
        float4 b4 = *reinterpret_cast<const float4*>(r1 + xq);
        float Lb = r1[xl], Rb = r1[xr];

        // y-blend 6 source cols
        float mL = gy * La + fy * Lb;
        float m0 = gy * a4.x + fy * b4.x;
        float m1 = gy * a4.y + fy * b4.y;
        float m2 = gy * a4.z + fy * b4.z;
        float m3 = gy * a4.w + fy * b4.w;
        float mR = gy * Ra + fy * Rb;

        // x-interp: out[2j]=0.25*in[j-1]+0.75*in[j]; out[2j+1]=0.75*in[j]+0.25*in[j+1]
        float tv[8];
        tv[0] = 0.25f * mL + 0.75f * m0;
        tv[1] = 0.75f * m0 + 0.25f * m1;
        tv[2] = 0.25f * m0 + 0.75f * m1;
        tv[3] = 0.75f * m1 + 0.25f * m2;
        tv[4] = 0.25f * m1 + 0.75f * m2;
        tv[5] = 0.75f * m2 + 0.25f * m3;
        tv[6] = 0.25f * m2 + 0.75f * m3;
        tv[7] = 0.75f * m3 + 0.25f * mR;

        const float* pr = pred + y * WW + 8 * u;
        float4 p0 = *reinterpret_cast<const float4*>(pr);
        float4 p1 = *reinterpret_cast<const float4*>(pr + 4);
        float pv[8] = {p0.x, p0.y, p0.z, p0.w, p1.x, p1.y, p1.z, p1.w};

#pragma unroll
        for (int j = 0; j < 8; ++j) {
            float d = pv[j] - tv[j];
            float l = d * d;
            sA += l;
            bool pos = tv[j] > 0.0f;
            sP += pos ? l : 0.0f;
            cP += pos ? 1 : 0;
        }
    }

    // wave64 shuffle reduce + LDS block reduce (5 waves)
    for (int off = 32; off > 0; off >>= 1) {
        sA += __shfl_down(sA, off);
        sP += __shfl_down(sP, off);
        cP += __shfl_down(cP, off);
    }
    __shared__ float shA[5], shP[5];
    __shared__ int shC[5];
    int w = tid >> 6;
    if ((tid & 63) == 0) { shA[w] = sA; shP[w] = sP; shC[w] = cP; }
    __syncthreads();
    if (tid == 0) {
        float a = 0.0f, p = 0.0f;
        int ci = 0;
        for (int q = 0; q < 5; ++q) { a += shA[q]; p += shP[q]; ci += shC[q]; }
        partA[s * BPS + blk] = a;
        partP[s * BPS + blk] = p;
        partC[s * BPS + blk] = ci;
    }
}

// ---------------- pass 2 (rare fallback): exact top-k when k < N-p ----------------
// 3-pass bit-histogram selection over losses of negative-target elements.
// Early-exits for this data regime (p ~ N/2 >> N/4).
__global__ __launch_bounds__(256) void k_topk(const float* __restrict__ x,
                                              const float* __restrict__ ct,
                                              const float* __restrict__ at,
                                              const int* __restrict__ partC,
                                              float* __restrict__ topk) {
    int s = blockIdx.x;
    __shared__ int pSh;
    if (threadIdx.x < 64) {
        int v = (threadIdx.x < BPS) ? partC[s * BPS + threadIdx.x] : 0;
        for (int off = 32; off > 0; off >>= 1) v += __shfl_down(v, off);
        if (threadIdx.x == 0) pSh = v;
    }
    __syncthreads();
    int p = pSh;
    int k = min((int)((float)p * 3.0f), NPIX - p);
    if (k < MINK || k >= NPIX - p) return;   // simple paths handled in k_final

    int b = s >> 1, c = s & 1;
    const float* pred = x + (size_t)s * NPIX;
    const float* tgt = (c == 0 ? ct : at) + (size_t)b * (TH * TW);

    __shared__ unsigned int hcnt[2048];
    __shared__ float hsum[2048];
    __shared__ unsigned int selBin;
    __shared__ unsigned int remShared;
    __shared__ float sumTopShared;

    if (threadIdx.x == 0) { remShared = (unsigned int)k; sumTopShared = 0.0f; }

    const int shiftv[3] = {21, 10, 0};
    const unsigned int maskv[3] = {0x7FFu, 0x7FFu, 0x3FFu};
    unsigned int prefix = 0;

    for (int pass = 0; pass < 3; ++pass) {
        for (int i = threadIdx.x; i < 2048; i += 256) { hcnt[i] = 0u; hsum[i] = 0.0f; }
        __syncthreads();
        for (int e = threadIdx.x; e < NPIX; e += 256) {
            int yy = e / WW, xx = e % WW;
            float tv = resize_scalar(tgt, yy, xx);
            if (tv > 0.0f) continue;          // positives excluded (-inf in ref)
            float d = pred[e] - tv;
            float l = d * d;                  // >= 0: uint bits order-preserving
            unsigned int bits = __float_as_uint(l);
            bool match;
            if (pass == 0) match = true;
            else if (pass == 1) match = ((bits >> 21) == prefix);
            else match = ((bits >> 10) == prefix);
            if (match) {
                unsigned int bin = (bits >> shiftv[pass]) & maskv[pass];
                atomicAdd(&hcnt[bin], 1u);
                atomicAdd(&hsum[bin], l);
            }
        }
        __syncthreads();
        if (threadIdx.x == 0) {
            unsigned int remS = remShared;
            int nb = (int)maskv[pass] + 1;
            unsigned int cum = 0; float sAbove = 0.0f; unsigned int bsel = 0;
            for (int bin = nb - 1; bin >= 0; --bin) {
                unsigned int cc = hcnt[bin];
                if (cum + cc >= remS) { bsel = (unsigned int)bin; break; }
                cum += cc; sAbove += hsum[bin];
            }
            selBin = bsel;
            remShared = remS - cum;
            sumTopShared += sAbove;
        }
        __syncthreads();
        if (pass == 0) prefix = selBin;
        else if (pass == 1) prefix = (prefix << 11) | selBin;
        __syncthreads();
    }
    if (threadIdx.x == 0) {
        unsigned int bits = (prefix << 10) | selBin;  // exact k-th largest value
        float v = __uint_as_float(bits);
        topk[s] = sumTopShared + (float)remShared * v;
    }
}

// ---------------- pass 3: sum partials, per-sample OHEM logic, final mean ----------------
__global__ void k_final(const float* __restrict__ partA, const float* __restrict__ partP,
                        const int* __restrict__ partC, const float* __restrict__ topk,
                        float* __restrict__ out) {
    int s = threadIdx.x;   // 64 threads == 1 wave
    float a = 0.0f, pp = 0.0f;
    int p = 0;
    const float4* pa4 = reinterpret_cast<const float4*>(partA + s * BPS);
    const float4* pp4 = reinterpret_cast<const float4*>(partP + s * BPS);
    const int4*   pc4 = reinterpret_cast<const int4*>(partC + s * BPS);
#pragma unroll
    for (int q = 0; q < BPS / 4; ++q) {
        float4 va = pa4[q]; a += va.x + va.y + va.z + va.w;
        float4 vp = pp4[q]; pp += vp.x + vp.y + vp.z + vp.w;
        int4 vc = pc4[q]; p += vc.x + vc.y + vc.z + vc.w;
    }
    int k = min((int)((float)p * 3.0f), NPIX - p);  // exact: 3p < 2^24
    float lossv;
    if (k < MINK) {
        lossv = a / (float)NPIX;
    } else {
        float nn = a - pp;                           // sumNeg
        float tsum = (k >= NPIX - p) ? nn : topk[s];
        lossv = pp / (float)max(p, 1) + tsum / (float)max(k, 1);
    }
    for (int off = 32; off > 0; off >>= 1) lossv += __shfl_down(lossv, off);
    if (s == 0) out[0] = lossv / 32.0f;   // mean over B of (char + aff)
}

extern "C" void kernel_launch(void* const* d_in, const int* in_sizes, int n_in,
                              void* d_out, int out_size, void* d_ws, size_t ws_size,
                              hipStream_t stream) {
    const float* x  = (const float*)d_in[0];
    const float* ct = (const float*)d_in[1];
    const float* at = (const float*)d_in[2];
    float* out = (float*)d_out;

    float* partA = (float*)d_ws;                 // NS*BPS floats
    float* partP = partA + NS * BPS;             // NS*BPS floats
    int*   partC = (int*)(partP + NS * BPS);     // NS*BPS ints
    float* topk  = (float*)(partC + NS * BPS);   // NS floats

    k_reduce<<<dim3(NS * BPS), dim3(TPB), 0, stream>>>(x, ct, at, partA, partP, partC);
    k_topk<<<dim3(NS), dim3(256), 0, stream>>>(x, ct, at, partC, topk);
    k_final<<<dim3(1), dim3(64), 0, stream>>>(partA, partP, partC, topk, out);
}